// Round 1
// 601.851 us; speedup vs baseline: 1.3491x; 1.3491x over previous
//
#include <hip/hip_runtime.h>

// LossClassInOut: pred, pseudo are [N=2e6, C=32] fp32. Output: scalar fp32.
//
// ws float layout (2176 floats):
//   [0,32) counts_a | [32,64) counts_b | [64,1088) sums_a[32][32]
//   [1088,2112) sums_b[32][32] | [2112,2144) intra_a | [2144,2176) intra_b
//
// R3: the register-prefetch (float4 P[8],Q[8]) spilled to scratch —
// WRITE_SIZE showed ~513 MB/pass of spill writes (131072 thr x 15 sweeps x
// 256 B = 503 MB + atomics). This version stages via
// __builtin_amdgcn_global_load_lds (no VGPR round-trip, nothing to spill),
// double-buffered wave-private LDS tiles, counted s_waitcnt vmcnt(16)
// pipeline (T3/T4): next tile's 16 loads stay in flight while current tile
// computes. XOR swizzle preserved by pre-swizzling the per-lane GLOBAL
// source (linear LDS dest), per rule 21. 137 KB LDS -> 1 block/CU, NBLK=256.

constexpr int CDIM = 32;
constexpr int NBLK = 256;            // 1 block/CU (137KB LDS), all resident
constexpr int ROWS_PER_BLOCK = 256;  // 4 waves * 64 rows

typedef __attribute__((ext_vector_type(8)))  short bf16x8;
typedef __attribute__((ext_vector_type(16))) float f32x16;

__device__ __forceinline__ unsigned short f2bf(float f) {
    unsigned u = __float_as_uint(f);
    return (unsigned short)((u + 0x7FFFu + ((u >> 16) & 1u)) >> 16);  // RNE
}
// float-index into a 64x32 tile stored as 128B rows with 16B-block XOR swizzle
__device__ __forceinline__ int toff(int r, int kb) {
    return r * 32 + ((kb ^ (r & 7)) * 4);
}
// np.argmax semantics: strict > keeps first index on ties
__device__ __forceinline__ int argmax_row(const float4* v) {
    float b = v[0].x; int bi = 0;
#pragma unroll
    for (int k = 0; k < 8; k++) {
        int k4 = k * 4;
        if (v[k].x > b) { b = v[k].x; bi = k4; }
        if (v[k].y > b) { b = v[k].y; bi = k4 + 1; }
        if (v[k].z > b) { b = v[k].z; bi = k4 + 2; }
        if (v[k].w > b) { b = v[k].w; bi = k4 + 3; }
    }
    return bi;
}

// Stage one 64x32 fp32 tile (rows wb..wb+63) into LDS via 8 global_load_lds
// dwordx4. LDS dest is linear (base + lane*16); the lane's global source
// block index is pre-XOR'd so the LDS content matches toff()'s layout.
__device__ __forceinline__ void stage_tile(const float4* __restrict__ g4,
                                           float* lds, long long wb,
                                           int nrows, int lw)
{
    const int rl = lw >> 3;
    const int kb = (lw & 7) ^ (rl & 7);    // pre-swizzled source block
#pragma unroll
    for (int i = 0; i < 8; i++) {
        long long r = wb + 8 * i + rl; if (r >= nrows) r = nrows - 1;
        __builtin_amdgcn_global_load_lds(
            (const __attribute__((address_space(1))) void*)(g4 + r * 8 + kb),
            (__attribute__((address_space(3))) void*)(lds + i * 256),
            16, 0, 0);
    }
}

__global__ __launch_bounds__(256) void pass1_kernel(
    const float* __restrict__ pred, const float* __restrict__ pseudo,
    float* __restrict__ ws, int nrows)
{
    __shared__ __align__(16) float ptile[4][2][64 * 32];
    __shared__ __align__(16) float qtile[4][2][64 * 32];
    __shared__ __align__(16) unsigned short labs[4][64];
    __shared__ float sa[CDIM][33], sb[CDIM][33];
    __shared__ float ca[CDIM], cb[CDIM];

    const int t = threadIdx.x, wv = t >> 6, lw = t & 63;
    for (int i = t; i < CDIM * 33; i += 256) { (&sa[0][0])[i] = 0.f; (&sb[0][0])[i] = 0.f; }
    if (t < CDIM) { ca[t] = 0.f; cb[t] = 0.f; }
    __syncthreads();

    const int n = lw & 31, h = lw >> 5;    // mfma lane coords

    f32x16 accP, accQ;
#pragma unroll
    for (int g = 0; g < 16; g++) { accP[g] = 0.f; accQ[g] = 0.f; }

    const float4* p4 = (const float4*)pred;
    const float4* q4 = (const float4*)pseudo;
    const long long rps = (long long)NBLK * ROWS_PER_BLOCK;
    const int nsweep = (int)((nrows + rps - 1) / rps);
    const long long wbase0 = (long long)blockIdx.x * ROWS_PER_BLOCK + wv * 64;

    // prologue: stage sweep 0 into buffer 0 (16 loads in flight)
    stage_tile(p4, ptile[wv][0], wbase0, nrows, lw);
    stage_tile(q4, qtile[wv][0], wbase0, nrows, lw);

    for (int s = 0; s < nsweep; s++) {
        const long long wb = wbase0 + (long long)s * rps;
        const int cur = s & 1;
        if (s + 1 < nsweep) {              // prefetch next sweep, then wait
            const long long wb2 = wb + rps;
            stage_tile(p4, ptile[wv][cur ^ 1], wb2, nrows, lw);
            stage_tile(q4, qtile[wv][cur ^ 1], wb2, nrows, lw);
            asm volatile("s_waitcnt vmcnt(16)" ::: "memory");  // drain cur, keep next
        } else {
            asm volatile("s_waitcnt vmcnt(0)" ::: "memory");
        }
        __builtin_amdgcn_sched_barrier(0);
        float* pt = ptile[wv][cur];
        float* qt = qtile[wv][cur];

        // per-lane labels from register tournament (lane lw owns tile-row lw)
        const bool valid = (wb + lw) < nrows;
        int la, lbv;
        {
            float4 r_[8];
#pragma unroll
            for (int k = 0; k < 8; k++) r_[k] = *(const float4*)&qt[toff(lw, k)];
            la = argmax_row(r_);
#pragma unroll
            for (int k = 0; k < 8; k++) r_[k] = *(const float4*)&pt[toff(lw, k)];
            lbv = argmax_row(r_);
        }
        labs[wv][lw] = (unsigned short)((valid ? la : 0xFF) | ((valid ? lbv : 0xFF) << 8));
        unsafeAtomicAdd(&ca[la  & 31], valid ? 1.f : 0.f);
        unsafeAtomicAdd(&cb[lbv & 31], valid ? 1.f : 0.f);

        // one-hot MFMA: sums[c][d] += onehot(label)^T * X over 64 rows (K-tiles of 16)
#pragma unroll
        for (int kt = 0; kt < 4; kt++) {
            const uint4 lv = *(const uint4*)&labs[wv][kt * 16 + h * 8];  // 8 rows' packed labels
            bf16x8 aP, aQ, bP, bQ;
#pragma unroll
            for (int j = 0; j < 8; j++) {
                unsigned w32 = ((const unsigned*)&lv)[j >> 1];
                unsigned pr  = (w32 >> ((j & 1) * 16)) & 0xFFFFu;
                int laj = (int)(pr & 0xFF), lbj = (int)(pr >> 8);
                aP[j] = (short)((laj == n) ? 0x3F80 : 0);   // bf16 1.0 / 0.0
                aQ[j] = (short)((lbj == n) ? 0x3F80 : 0);
                int r = kt * 16 + h * 8 + j;
                int o = r * 32 + (((n >> 2) ^ (r & 7)) * 4) + (n & 3);
                bP[j] = (short)f2bf(pt[o]);
                bQ[j] = (short)f2bf(qt[o]);
            }
            accP = __builtin_amdgcn_mfma_f32_32x32x16_bf16(aP, bP, accP, 0, 0, 0);
            accQ = __builtin_amdgcn_mfma_f32_32x32x16_bf16(aQ, bQ, accQ, 0, 0, 0);
        }
    }

    // fold wave accumulators: C/D layout col=lane&31, row=(reg&3)+8*(reg>>2)+4*(lane>>5)
#pragma unroll
    for (int g = 0; g < 16; g++) {
        int c = (g & 3) + 8 * (g >> 2) + 4 * h;
        unsafeAtomicAdd(&sa[c][n], accP[g]);
        unsafeAtomicAdd(&sb[c][n], accQ[g]);
    }
    __syncthreads();
    for (int i = t; i < CDIM * CDIM; i += 256) {
        int c = i >> 5, d = i & 31;
        unsafeAtomicAdd(&ws[64 + i],        sa[c][d]);
        unsafeAtomicAdd(&ws[64 + 1024 + i], sb[c][d]);
    }
    if (t < CDIM) { unsafeAtomicAdd(&ws[t], ca[t]); unsafeAtomicAdd(&ws[32 + t], cb[t]); }
}

__global__ __launch_bounds__(256) void pass2_kernel(
    const float* __restrict__ pred, const float* __restrict__ pseudo,
    float* __restrict__ ws, int nrows)
{
    __shared__ __align__(16) float ptile[4][2][64 * 32];
    __shared__ __align__(16) float qtile[4][2][64 * 32];
    __shared__ __align__(16) float mA[1024], mB[1024];
    __shared__ float ia[CDIM], ib[CDIM];

    const int t = threadIdx.x, wv = t >> 6, lw = t & 63;
    for (int i = t; i < 1024; i += 256) {     // means, stored XOR-swizzled like tiles
        int c = i >> 5, d = i & 31;
        int o = c * 32 + (((d >> 2) ^ (c & 7)) * 4) + (d & 3);
        mA[o] = ws[64 + i]        / fmaxf(ws[c],      1.f);
        mB[o] = ws[64 + 1024 + i] / fmaxf(ws[32 + c], 1.f);
    }
    if (t < CDIM) { ia[t] = 0.f; ib[t] = 0.f; }
    __syncthreads();

    const float4* p4 = (const float4*)pred;
    const float4* q4 = (const float4*)pseudo;
    const long long rps = (long long)NBLK * ROWS_PER_BLOCK;
    const int nsweep = (int)((nrows + rps - 1) / rps);
    const long long wbase0 = (long long)blockIdx.x * ROWS_PER_BLOCK + wv * 64;

    stage_tile(p4, ptile[wv][0], wbase0, nrows, lw);
    stage_tile(q4, qtile[wv][0], wbase0, nrows, lw);

    for (int s = 0; s < nsweep; s++) {
        const long long wb = wbase0 + (long long)s * rps;
        const int cur = s & 1;
        if (s + 1 < nsweep) {
            const long long wb2 = wb + rps;
            stage_tile(p4, ptile[wv][cur ^ 1], wb2, nrows, lw);
            stage_tile(q4, qtile[wv][cur ^ 1], wb2, nrows, lw);
            asm volatile("s_waitcnt vmcnt(16)" ::: "memory");
        } else {
            asm volatile("s_waitcnt vmcnt(0)" ::: "memory");
        }
        __builtin_amdgcn_sched_barrier(0);
        float* pt = ptile[wv][cur];
        float* qt = qtile[wv][cur];

        const bool valid = (wb + lw) < nrows;
        float4 pr[8], qr[8];
#pragma unroll
        for (int k = 0; k < 8; k++) { pr[k] = *(const float4*)&pt[toff(lw, k)];
                                      qr[k] = *(const float4*)&qt[toff(lw, k)]; }
        const int la = argmax_row(qr) & 31;   // pseudo label -> segments pred
        const int lb = argmax_row(pr) & 31;   // pred label   -> segments pseudo
        float sA = 0.f, sB = 0.f;
#pragma unroll
        for (int k = 0; k < 8; k++) {
            float4 m4 = *(const float4*)&mA[la * 32 + ((k ^ (la & 7)) * 4)];
            sA += fabsf(pr[k].x - m4.x) + fabsf(pr[k].y - m4.y)
                + fabsf(pr[k].z - m4.z) + fabsf(pr[k].w - m4.w);
            float4 n4 = *(const float4*)&mB[lb * 32 + ((k ^ (lb & 7)) * 4)];
            sB += fabsf(qr[k].x - n4.x) + fabsf(qr[k].y - n4.y)
                + fabsf(qr[k].z - n4.z) + fabsf(qr[k].w - n4.w);
        }
        unsafeAtomicAdd(&ia[la], valid ? sA : 0.f);
        unsafeAtomicAdd(&ib[lb], valid ? sB : 0.f);
    }
    __syncthreads();
    if (t < CDIM) {
        unsafeAtomicAdd(&ws[2112 + t], ia[t]);
        unsafeAtomicAdd(&ws[2144 + t], ib[t]);
    }
}

__global__ __launch_bounds__(64) void finalize_kernel(
    const float* __restrict__ ws, float* __restrict__ out, int nrows)
{
    __shared__ float tota[CDIM];
    __shared__ float totb[CDIM];
    int t = threadIdx.x;   // lanes 0..31 = tensor a, 32..63 = tensor b
    if (t < CDIM) {
        float sa_ = 0.f, sb_ = 0.f;
        for (int c = 0; c < CDIM; c++) {
            sa_ += ws[64 + c * 32 + t];
            sb_ += ws[64 + 1024 + c * 32 + t];
        }
        tota[t] = sa_; totb[t] = sb_;
    }
    __syncthreads();

    const int  c   = t & 31;
    const bool isA = (t < 32);
    const float* sums = isA ? (ws + 64) : (ws + 64 + 1024);
    const float* tot  = isA ? tota : totb;
    float cnt  = isA ? ws[c]        : ws[32 + c];
    float isum = isA ? ws[2112 + c] : ws[2144 + c];

    float safe = fmaxf(cnt, 1.0f);
    float invs = 1.0f / safe;
    float invo = 1.0f / fmaxf((float)nrows - cnt, 1.0f);
    float mad = 0.f;
    for (int d = 0; d < CDIM; d++) {
        float s = sums[c * 32 + d];
        float m = s * invs;
        float o = (tot[d] - s) * invo;
        mad += fabsf(m - o);
    }
    mad *= (1.0f / CDIM);
    float diff = expf(-5.0f * mad);
    float present = (cnt > 0.f) ? 1.f : 0.f;

    unsigned long long pm = __ballot(cnt > 0.f);
    int np = isA ? __popcll(pm & 0xFFFFFFFFull) : __popcll(pm >> 32);
    if (np <= 1) diff = 1.0f;

    float intra   = isum * invs * (1.0f / CDIM);
    float contrib = present * (intra + diff);
    float pres    = present;
#pragma unroll
    for (int m = 1; m < 64; m <<= 1) {
        contrib += __shfl_xor(contrib, m, 64);
        pres    += __shfl_xor(pres,    m, 64);
    }
    if (t == 0) out[0] = contrib / (2.0f * pres);
}

extern "C" void kernel_launch(void* const* d_in, const int* in_sizes, int n_in,
                              void* d_out, int out_size, void* d_ws, size_t ws_size,
                              hipStream_t stream) {
    const float* pred   = (const float*)d_in[0];
    const float* pseudo = (const float*)d_in[1];
    float* ws  = (float*)d_ws;
    float* out = (float*)d_out;
    const int nrows = in_sizes[0] / CDIM;   // 2,000,000

    hipMemsetAsync(d_ws, 0, 2176 * sizeof(float), stream);

    dim3 grid(NBLK), block(256);
    pass1_kernel<<<grid, block, 0, stream>>>(pred, pseudo, ws, nrows);
    pass2_kernel<<<grid, block, 0, stream>>>(pred, pseudo, ws, nrows);
    finalize_kernel<<<1, 64, 0, stream>>>(ws, out, nrows);
}

// Round 2
// 601.014 us; speedup vs baseline: 1.3509x; 1.0014x over previous
//
#include <hip/hip_runtime.h>

// LossClassInOut: pred, pseudo are [N=2e6, C=32] fp32. Output: scalar fp32.
//
// ws float layout (2176 floats):
//   [0,32) counts_a | [32,64) counts_b | [64,1088) sums_a[32][32]
//   [1088,2112) sums_b[32][32] | [2112,2144) intra_a | [2144,2176) intra_b
//
// R4: R3 fixed the spill (WRITE 513->2 MB) but left 1 block/CU (140KB LDS)
// = 1 wave/SIMD; 83% of cycles were unhidden stall (VALUBusy 17%, HBM 16%).
// This version: 32-row wave tiles (74KB LDS -> 2 blocks/CU, 2 waves/SIMD,
// NBLK=512) and pair-split argmax (lane r / r+32 each scan 16 cols, combine
// via 2 shfl_xor) -- halves argmax reads+tournament depth and cuts the b128
// bank conflict from 8-way to 4-way. Staging stays global_load_lds with
// pre-swizzled source + counted vmcnt(8) double-buffer pipeline.

constexpr int CDIM = 32;
constexpr int NBLK = 512;            // 2 blocks/CU (74KB LDS each), all resident
constexpr int ROWS_PER_BLOCK = 128;  // 4 waves * 32 rows

typedef __attribute__((ext_vector_type(8)))  short bf16x8;
typedef __attribute__((ext_vector_type(16))) float f32x16;

__device__ __forceinline__ unsigned short f2bf(float f) {
    unsigned u = __float_as_uint(f);
    return (unsigned short)((u + 0x7FFFu + ((u >> 16) & 1u)) >> 16);  // RNE
}
// float-index into a 32x32 tile stored as 128B rows with 16B-block XOR swizzle
__device__ __forceinline__ int toff(int r, int kb) {
    return r * 32 + ((kb ^ (r & 7)) * 4);
}
// np.argmax over 16 values (4 float4), strict > keeps first index
__device__ __forceinline__ void argmax16(const float4* v, float& bv, int& bi) {
    float b = v[0].x; int i = 0;
#pragma unroll
    for (int k = 0; k < 4; k++) {
        int k4 = k * 4;
        if (v[k].x > b) { b = v[k].x; i = k4; }
        if (v[k].y > b) { b = v[k].y; i = k4 + 1; }
        if (v[k].z > b) { b = v[k].z; i = k4 + 2; }
        if (v[k].w > b) { b = v[k].w; i = k4 + 3; }
    }
    bv = b; bi = i;
}
// combine half-row argmax across lane pair (lw ^ 32); ties favor lower col
__device__ __forceinline__ int combine_argmax(float bv, int bc, int h2) {
    float ov = __shfl_xor(bv, 32);
    int   oc = __shfl_xor(bc, 32);
    float vlo = h2 ? ov : bv, vhi = h2 ? bv : ov;
    int   clo = h2 ? oc : bc, chi = h2 ? bc : oc;
    return (vhi > vlo) ? chi : clo;
}

// Stage one 32x32 fp32 tile (rows wb..wb+31) into LDS via 4 global_load_lds
// dwordx4. LDS dest linear (base + lane*16); the lane's global source block
// is pre-XOR'd so LDS content matches toff()'s swizzled layout (rule 21).
__device__ __forceinline__ void stage_tile(const float4* __restrict__ g4,
                                           float* lds, long long wb,
                                           int nrows, int lw)
{
    const int rl = lw >> 3;
    const int kb = (lw & 7) ^ (rl & 7);    // pre-swizzled source block
#pragma unroll
    for (int i = 0; i < 4; i++) {
        long long r = wb + 8 * i + rl; if (r >= nrows) r = nrows - 1;
        __builtin_amdgcn_global_load_lds(
            (const __attribute__((address_space(1))) void*)(g4 + r * 8 + kb),
            (__attribute__((address_space(3))) void*)(lds + i * 256),
            16, 0, 0);
    }
}

__global__ __launch_bounds__(256) void pass1_kernel(
    const float* __restrict__ pred, const float* __restrict__ pseudo,
    float* __restrict__ ws, int nrows)
{
    __shared__ __align__(16) float ptile[4][2][32 * 32];
    __shared__ __align__(16) float qtile[4][2][32 * 32];
    __shared__ __align__(16) unsigned short labs[4][32];
    __shared__ float sa[CDIM][33], sb[CDIM][33];
    __shared__ float ca[CDIM], cb[CDIM];

    const int t = threadIdx.x, wv = t >> 6, lw = t & 63;
    for (int i = t; i < CDIM * 33; i += 256) { (&sa[0][0])[i] = 0.f; (&sb[0][0])[i] = 0.f; }
    if (t < CDIM) { ca[t] = 0.f; cb[t] = 0.f; }
    __syncthreads();

    const int n = lw & 31, h2 = lw >> 5;   // mfma/argmax lane coords

    f32x16 accP, accQ;
#pragma unroll
    for (int g = 0; g < 16; g++) { accP[g] = 0.f; accQ[g] = 0.f; }

    const float4* p4 = (const float4*)pred;
    const float4* q4 = (const float4*)pseudo;
    const long long rps = (long long)NBLK * ROWS_PER_BLOCK;
    const int nsweep = (int)((nrows + rps - 1) / rps);
    const long long wbase0 = (long long)blockIdx.x * ROWS_PER_BLOCK + wv * 32;

    // prologue: stage sweep 0 into buffer 0 (8 loads in flight)
    stage_tile(p4, ptile[wv][0], wbase0, nrows, lw);
    stage_tile(q4, qtile[wv][0], wbase0, nrows, lw);

    for (int s = 0; s < nsweep; s++) {
        const long long wb = wbase0 + (long long)s * rps;
        const int cur = s & 1;
        if (s + 1 < nsweep) {              // prefetch next sweep, then wait
            const long long wb2 = wb + rps;
            stage_tile(p4, ptile[wv][cur ^ 1], wb2, nrows, lw);
            stage_tile(q4, qtile[wv][cur ^ 1], wb2, nrows, lw);
            asm volatile("s_waitcnt vmcnt(8)" ::: "memory");  // drain cur, keep next
        } else {
            asm volatile("s_waitcnt vmcnt(0)" ::: "memory");
        }
        __builtin_amdgcn_sched_barrier(0);
        float* pt = ptile[wv][cur];
        float* qt = qtile[wv][cur];

        // pair-split labels: lane lw scans cols 16*h2..16*h2+15 of row lw&31
        const int r = n;                   // tile row this lane helps with
        const bool valid = (wb + r) < nrows;
        int la, lbv;
        {
            float4 v_[4];
#pragma unroll
            for (int k = 0; k < 4; k++) v_[k] = *(const float4*)&qt[toff(r, 4 * h2 + k)];
            float bv; int bi; argmax16(v_, bv, bi);
            la = combine_argmax(bv, 16 * h2 + bi, h2);
#pragma unroll
            for (int k = 0; k < 4; k++) v_[k] = *(const float4*)&pt[toff(r, 4 * h2 + k)];
            argmax16(v_, bv, bi);
            lbv = combine_argmax(bv, 16 * h2 + bi, h2);
        }
        if (h2 == 0) {
            labs[wv][r] = (unsigned short)((valid ? la : 0xFF) | ((valid ? lbv : 0xFF) << 8));
            unsafeAtomicAdd(&ca[la & 31], valid ? 1.f : 0.f);
            unsafeAtomicAdd(&cb[lbv & 31], valid ? 1.f : 0.f);
        }

        // one-hot MFMA: sums[c][d] += onehot(label)^T * X over 32 rows (K-tiles of 16)
#pragma unroll
        for (int kt = 0; kt < 2; kt++) {
            const uint4 lv = *(const uint4*)&labs[wv][kt * 16 + h2 * 8];  // 8 rows' packed labels
            bf16x8 aP, aQ, bP, bQ;
#pragma unroll
            for (int j = 0; j < 8; j++) {
                unsigned w32 = ((const unsigned*)&lv)[j >> 1];
                unsigned pr  = (w32 >> ((j & 1) * 16)) & 0xFFFFu;
                int laj = (int)(pr & 0xFF), lbj = (int)(pr >> 8);
                aP[j] = (short)((laj == n) ? 0x3F80 : 0);   // bf16 1.0 / 0.0
                aQ[j] = (short)((lbj == n) ? 0x3F80 : 0);
                int rr = kt * 16 + h2 * 8 + j;
                int o = rr * 32 + (((n >> 2) ^ (rr & 7)) * 4) + (n & 3);
                bP[j] = (short)f2bf(pt[o]);
                bQ[j] = (short)f2bf(qt[o]);
            }
            accP = __builtin_amdgcn_mfma_f32_32x32x16_bf16(aP, bP, accP, 0, 0, 0);
            accQ = __builtin_amdgcn_mfma_f32_32x32x16_bf16(aQ, bQ, accQ, 0, 0, 0);
        }
    }

    // fold wave accumulators: C/D layout col=lane&31, row=(reg&3)+8*(reg>>2)+4*(lane>>5)
#pragma unroll
    for (int g = 0; g < 16; g++) {
        int c = (g & 3) + 8 * (g >> 2) + 4 * h2;
        unsafeAtomicAdd(&sa[c][n], accP[g]);
        unsafeAtomicAdd(&sb[c][n], accQ[g]);
    }
    __syncthreads();
    for (int i = t; i < CDIM * CDIM; i += 256) {
        int c = i >> 5, d = i & 31;
        unsafeAtomicAdd(&ws[64 + i],        sa[c][d]);
        unsafeAtomicAdd(&ws[64 + 1024 + i], sb[c][d]);
    }
    if (t < CDIM) { unsafeAtomicAdd(&ws[t], ca[t]); unsafeAtomicAdd(&ws[32 + t], cb[t]); }
}

__global__ __launch_bounds__(256) void pass2_kernel(
    const float* __restrict__ pred, const float* __restrict__ pseudo,
    float* __restrict__ ws, int nrows)
{
    __shared__ __align__(16) float ptile[4][2][32 * 32];
    __shared__ __align__(16) float qtile[4][2][32 * 32];
    __shared__ __align__(16) float mA[1024], mB[1024];
    __shared__ float ia[CDIM], ib[CDIM];

    const int t = threadIdx.x, wv = t >> 6, lw = t & 63;
    for (int i = t; i < 1024; i += 256) {     // means, stored XOR-swizzled like tiles
        int c = i >> 5, d = i & 31;
        int o = c * 32 + (((d >> 2) ^ (c & 7)) * 4) + (d & 3);
        mA[o] = ws[64 + i]        / fmaxf(ws[c],      1.f);
        mB[o] = ws[64 + 1024 + i] / fmaxf(ws[32 + c], 1.f);
    }
    if (t < CDIM) { ia[t] = 0.f; ib[t] = 0.f; }
    __syncthreads();

    const int n = lw & 31, h2 = lw >> 5;

    const float4* p4 = (const float4*)pred;
    const float4* q4 = (const float4*)pseudo;
    const long long rps = (long long)NBLK * ROWS_PER_BLOCK;
    const int nsweep = (int)((nrows + rps - 1) / rps);
    const long long wbase0 = (long long)blockIdx.x * ROWS_PER_BLOCK + wv * 32;

    stage_tile(p4, ptile[wv][0], wbase0, nrows, lw);
    stage_tile(q4, qtile[wv][0], wbase0, nrows, lw);

    for (int s = 0; s < nsweep; s++) {
        const long long wb = wbase0 + (long long)s * rps;
        const int cur = s & 1;
        if (s + 1 < nsweep) {
            const long long wb2 = wb + rps;
            stage_tile(p4, ptile[wv][cur ^ 1], wb2, nrows, lw);
            stage_tile(q4, qtile[wv][cur ^ 1], wb2, nrows, lw);
            asm volatile("s_waitcnt vmcnt(8)" ::: "memory");
        } else {
            asm volatile("s_waitcnt vmcnt(0)" ::: "memory");
        }
        __builtin_amdgcn_sched_barrier(0);
        float* pt = ptile[wv][cur];
        float* qt = qtile[wv][cur];

        const int r = n;
        const bool valid = (wb + r) < nrows;
        float4 pr_[4], qr_[4];
#pragma unroll
        for (int k = 0; k < 4; k++) { pr_[k] = *(const float4*)&pt[toff(r, 4 * h2 + k)];
                                      qr_[k] = *(const float4*)&qt[toff(r, 4 * h2 + k)]; }
        float bv; int bi;
        argmax16(qr_, bv, bi);
        const int la = combine_argmax(bv, 16 * h2 + bi, h2) & 31;  // pseudo label -> segments pred
        argmax16(pr_, bv, bi);
        const int lb = combine_argmax(bv, 16 * h2 + bi, h2) & 31;  // pred label   -> segments pseudo

        float sA = 0.f, sB = 0.f;
#pragma unroll
        for (int k = 0; k < 4; k++) {
            float4 m4 = *(const float4*)&mA[la * 32 + (((4 * h2 + k) ^ (la & 7)) * 4)];
            sA += fabsf(pr_[k].x - m4.x) + fabsf(pr_[k].y - m4.y)
                + fabsf(pr_[k].z - m4.z) + fabsf(pr_[k].w - m4.w);
            float4 n4 = *(const float4*)&mB[lb * 32 + (((4 * h2 + k) ^ (lb & 7)) * 4)];
            sB += fabsf(qr_[k].x - n4.x) + fabsf(qr_[k].y - n4.y)
                + fabsf(qr_[k].z - n4.z) + fabsf(qr_[k].w - n4.w);
        }
        unsafeAtomicAdd(&ia[la], valid ? sA : 0.f);   // both half-lanes contribute
        unsafeAtomicAdd(&ib[lb], valid ? sB : 0.f);
    }
    __syncthreads();
    if (t < CDIM) {
        unsafeAtomicAdd(&ws[2112 + t], ia[t]);
        unsafeAtomicAdd(&ws[2144 + t], ib[t]);
    }
}

__global__ __launch_bounds__(64) void finalize_kernel(
    const float* __restrict__ ws, float* __restrict__ out, int nrows)
{
    __shared__ float tota[CDIM];
    __shared__ float totb[CDIM];
    int t = threadIdx.x;   // lanes 0..31 = tensor a, 32..63 = tensor b
    if (t < CDIM) {
        float sa_ = 0.f, sb_ = 0.f;
        for (int c = 0; c < CDIM; c++) {
            sa_ += ws[64 + c * 32 + t];
            sb_ += ws[64 + 1024 + c * 32 + t];
        }
        tota[t] = sa_; totb[t] = sb_;
    }
    __syncthreads();

    const int  c   = t & 31;
    const bool isA = (t < 32);
    const float* sums = isA ? (ws + 64) : (ws + 64 + 1024);
    const float* tot  = isA ? tota : totb;
    float cnt  = isA ? ws[c]        : ws[32 + c];
    float isum = isA ? ws[2112 + c] : ws[2144 + c];

    float safe = fmaxf(cnt, 1.0f);
    float invs = 1.0f / safe;
    float invo = 1.0f / fmaxf((float)nrows - cnt, 1.0f);
    float mad = 0.f;
    for (int d = 0; d < CDIM; d++) {
        float s = sums[c * 32 + d];
        float m = s * invs;
        float o = (tot[d] - s) * invo;
        mad += fabsf(m - o);
    }
    mad *= (1.0f / CDIM);
    float diff = expf(-5.0f * mad);
    float present = (cnt > 0.f) ? 1.f : 0.f;

    unsigned long long pm = __ballot(cnt > 0.f);
    int np = isA ? __popcll(pm & 0xFFFFFFFFull) : __popcll(pm >> 32);
    if (np <= 1) diff = 1.0f;

    float intra   = isum * invs * (1.0f / CDIM);
    float contrib = present * (intra + diff);
    float pres    = present;
#pragma unroll
    for (int m = 1; m < 64; m <<= 1) {
        contrib += __shfl_xor(contrib, m, 64);
        pres    += __shfl_xor(pres,    m, 64);
    }
    if (t == 0) out[0] = contrib / (2.0f * pres);
}

extern "C" void kernel_launch(void* const* d_in, const int* in_sizes, int n_in,
                              void* d_out, int out_size, void* d_ws, size_t ws_size,
                              hipStream_t stream) {
    const float* pred   = (const float*)d_in[0];
    const float* pseudo = (const float*)d_in[1];
    float* ws  = (float*)d_ws;
    float* out = (float*)d_out;
    const int nrows = in_sizes[0] / CDIM;   // 2,000,000

    hipMemsetAsync(d_ws, 0, 2176 * sizeof(float), stream);

    dim3 grid(NBLK), block(256);
    pass1_kernel<<<grid, block, 0, stream>>>(pred, pseudo, ws, nrows);
    pass2_kernel<<<grid, block, 0, stream>>>(pred, pseudo, ws, nrows);
    finalize_kernel<<<1, 64, 0, stream>>>(ws, out, nrows);
}